// Round 25
// baseline (82.313 us; speedup 1.0000x reference)
//
#include <hip/hip_runtime.h>
#include <hip/hip_fp8.h>
#include <math.h>

#define L      2048
#define DDIM   512
#define NBATCH 8
#define NTILE  16                        // 128-row tiles
#define NPAIR  (NTILE * (NTILE + 1) / 2) // 136
#define SCREEN_BLOCKS (NBATCH * NPAIR)   // 1088

#define ALPHA  0.1
#define BETA   0.3
#define PAN2   2048      // bytes per packed 32-row x 64-dim fp8 panel
#define NL     (NBATCH * L)

typedef __attribute__((ext_vector_type(16))) float f32x16;
typedef long long2v __attribute__((ext_vector_type(2)));

// ---------------------------------------------------------------------------
// K1 (fused): group sums (register accumulators, NO LDS-RMW) + fp8 packing of
// the first 64 dims + per-half row-sq. grid 512 = 8 n x 16 chunk x 4 qtr;
// 256 thr = 8 row-parts x 32 dims. Blocks with c<2 also pack their 32-dim
// chunk into the R20-verified MFMA-fragment layout and write sqh[c].
// ---------------------------------------------------------------------------
__global__ __launch_bounds__(256) void fused_kernel(const float* __restrict__ pred,
                                                    const int*   __restrict__ seg,
                                                    float* __restrict__ Spart,
                                                    float* __restrict__ Tpart,
                                                    float* __restrict__ sqh,
                                                    unsigned char* __restrict__ h8) {
    __shared__ float Sl[8][16][32];
    __shared__ float Tl[8][16][32];
    __shared__ unsigned char f8l[512][32];
    __shared__ float sql[512];

    int bid = blockIdx.x;
    int n   = bid & 7;
    int c   = (bid >> 3) & 15;
    int qtr = bid >> 7;
    int t = threadIdx.x;
    int d = t & 31, p = t >> 5;

    float sacc[16], tacc[16];
    #pragma unroll
    for (int g = 0; g < 16; ++g) { sacc[g] = 0.0f; tacc[g] = 0.0f; }

    const float* pb   = pred + (size_t)n * L * DDIM + c * 32 + d;
    const int*   segb = seg + n * L + qtr * 512;
    const bool packer = (c < 2);

    #pragma unroll 2
    for (int i = 0; i < 64; ++i) {
        int lr  = i * 8 + p;                       // 0..511 within quarter
        float x = pb[(size_t)(qtr * 512 + lr) * DDIM];
        int g   = segb[lr];
        float x2 = x * x;
        #pragma unroll
        for (int gg = 0; gg < 16; ++gg) {
            bool sel = (g == gg);
            sacc[gg] += sel ? x : 0.0f;
            tacc[gg] += sel ? x2 : 0.0f;
        }
        if (packer) {
            __hip_fp8_e4m3 f8(x);
            f8l[lr][d] = f8.__x;
            float rs = x2;
            #pragma unroll
            for (int off = 16; off > 0; off >>= 1) rs += __shfl_xor(rs, off, 32);
            if (d == 0) sql[lr] = rs;
        }
    }

    #pragma unroll
    for (int gg = 0; gg < 16; ++gg) {
        Sl[p][gg][d] = sacc[gg];
        Tl[p][gg][d] = tacc[gg];
    }
    __syncthreads();

    for (int i = t; i < 512; i += 256) {
        int g = i >> 5, dd = i & 31;
        float s = 0.0f, tt = 0.0f;
        #pragma unroll
        for (int q = 0; q < 8; ++q) { s += Sl[q][g][dd]; tt += Tl[q][g][dd]; }
        Spart[((size_t)bid * 16 + g) * 32 + dd] = s;
        Sl[0][g][dd] = tt;
    }
    __syncthreads();
    if (t < 16) {
        float tt = 0.0f;
        #pragma unroll
        for (int dd = 0; dd < 32; ++dd) tt += Sl[0][t][dd];
        Tpart[bid * 16 + t] = tt;
    }

    if (packer) {
        // pack write-out: 2048 8B units; unit u = (pn, r5, kodd, khalf);
        // dims of unit = c*32 + (kodd*2+khalf)*8 .. +7 (R20-verified layout)
        for (int u = t; u < 2048; u += 256) {
            int pn    = u >> 7;
            int r5    = (u >> 2) & 31;
            int kodd  = (u >> 1) & 1;
            int khalf = u & 1;
            const unsigned char* src = &f8l[pn * 32 + r5][(kodd * 2 + khalf) * 8];
            size_t off = (size_t)(n * 64 + qtr * 16 + pn) * PAN2 + c * 1024
                       + (r5 + 32 * khalf) * 16 + kodd * 8;
            *(unsigned long long*)(h8 + off) = *(const unsigned long long*)src;
        }
        float* sqdst = sqh + (size_t)c * NL + n * L + qtr * 512;
        for (int r = t; r < 512; r += 256) sqdst[r] = sql[r];
    }
}

// ---------------------------------------------------------------------------
// K2: 64-dim fp8 screen GEMM (register-direct, R21-verified). LDS prologue
// builds sq64/n64 for the block's 256 rows from sqh halves (no global
// gathers in the epilogue). Certifies hinge==0 when d2e >= 4.5+0.27*nj*nk;
// survivors -> exact fp32 fallback. Per-block partial -> hpart[bid].
// ---------------------------------------------------------------------------
__global__ __launch_bounds__(256) void screen_kernel(
        const unsigned char* __restrict__ h8,
        const float* __restrict__ sqh,
        const int*   __restrict__ seg,
        const float* __restrict__ pred,
        double* __restrict__ hpart) {
    __shared__ float sqn[256];
    __shared__ float nn[256];
    __shared__ double wred[4];

    int bid = blockIdx.x;
    int n = bid & 7;
    int p = bid >> 3;
    int tj = 0;
    while (true) {
        int rl2 = NTILE - tj;
        if (p < rl2) break;
        p -= rl2;
        ++tj;
    }
    int tk = tj + p;

    int t    = threadIdx.x;
    int wid  = t >> 6;
    int lane = t & 63;
    int wr   = wid >> 1, wc = wid & 1;
    int l31  = lane & 31;
    int hsel = lane >> 5;

    // prologue: sq/n for rows of the A tile (0..127) and B tile (128..255)
    {
        int r   = (t < 128) ? (tj * 128 + t) : (tk * 128 + (t - 128));
        float s = sqh[(size_t)n * L + r] + sqh[(size_t)NL + n * L + r];
        sqn[t] = s;
        nn[t]  = sqrtf(s);
    }
    __syncthreads();

    const unsigned char* pa0 = h8 + (size_t)(n * 64 + tj * 4 + wr * 2 + 0) * PAN2 + lane * 16;
    const unsigned char* pa1 = pa0 + PAN2;
    const unsigned char* pb0 = h8 + (size_t)(n * 64 + tk * 4 + wc * 2 + 0) * PAN2 + lane * 16;
    const unsigned char* pb1 = pb0 + PAN2;

    f32x16 acc[2][2];
    #pragma unroll
    for (int m = 0; m < 2; ++m)
        #pragma unroll
        for (int nf = 0; nf < 2; ++nf)
            #pragma unroll
            for (int x = 0; x < 16; ++x) acc[m][nf][x] = 0.0f;

    #pragma unroll
    for (int ks2 = 0; ks2 < 2; ++ks2) {
        long2v a0 = *(const long2v*)(pa0 + ks2 * 1024);
        long2v a1 = *(const long2v*)(pa1 + ks2 * 1024);
        long2v b0 = *(const long2v*)(pb0 + ks2 * 1024);
        long2v b1 = *(const long2v*)(pb1 + ks2 * 1024);
        acc[0][0] = __builtin_amdgcn_mfma_f32_32x32x16_fp8_fp8(a0.x, b0.x, acc[0][0], 0, 0, 0);
        acc[0][1] = __builtin_amdgcn_mfma_f32_32x32x16_fp8_fp8(a0.x, b1.x, acc[0][1], 0, 0, 0);
        acc[1][0] = __builtin_amdgcn_mfma_f32_32x32x16_fp8_fp8(a1.x, b0.x, acc[1][0], 0, 0, 0);
        acc[1][1] = __builtin_amdgcn_mfma_f32_32x32x16_fp8_fp8(a1.x, b1.x, acc[1][1], 0, 0, 0);
        acc[0][0] = __builtin_amdgcn_mfma_f32_32x32x16_fp8_fp8(a0.y, b0.y, acc[0][0], 0, 0, 0);
        acc[0][1] = __builtin_amdgcn_mfma_f32_32x32x16_fp8_fp8(a0.y, b1.y, acc[0][1], 0, 0, 0);
        acc[1][0] = __builtin_amdgcn_mfma_f32_32x32x16_fp8_fp8(a1.y, b0.y, acc[1][0], 0, 0, 0);
        acc[1][1] = __builtin_amdgcn_mfma_f32_32x32x16_fp8_fp8(a1.y, b1.y, acc[1][1], 0, 0, 0);
    }

    const int* segb = seg + n * L;

    double hsum = 0.0;
    #pragma unroll
    for (int nf = 0; nf < 2; ++nf) {
        int kl = wc * 64 + nf * 32 + l31;          // local B row
        int k  = tk * 128 + kl;
        float sqk = sqn[128 + kl];
        float nk  = nn[128 + kl];
        int   sgk = segb[k];
        #pragma unroll
        for (int m = 0; m < 2; ++m)
            #pragma unroll
            for (int x = 0; x < 16; ++x) {
                int jl = wr * 64 + m * 32 + (x & 3) + 8 * (x >> 2) + 4 * hsel;
                int j  = tj * 128 + jl;
                if (j >= k) continue;
                if (segb[j] == sgk) continue;
                float d2e = sqn[jl] + sqk - 2.0f * acc[m][nf][x];
                float thr = 4.5f + 0.27f * nn[jl] * nk;
                if (d2e >= thr) continue;          // certified hinge == 0
                const float* pj  = pred + (size_t)(n * L + j) * DDIM;
                const float* pk2 = pred + (size_t)(n * L + k) * DDIM;
                float d2x = 0.0f;
                for (int dd = 0; dd < DDIM; ++dd) {
                    float df = pj[dd] - pk2[dd];
                    d2x = fmaf(df, df, d2x);
                }
                if (d2x < 4.0f) {
                    float dist = sqrtf(d2x);
                    float hg = 2.0f - dist;
                    hsum += (double)hg * (double)hg * 2.0;   // weight 2 (j<k)
                }
            }
    }

    #pragma unroll
    for (int off = 32; off > 0; off >>= 1)
        hsum += __shfl_down(hsum, off);
    if (lane == 0) wred[wid] = hsum;
    __syncthreads();
    if (t == 0) hpart[bid] = (wred[0] + wred[1]) + (wred[2] + wred[3]);
}

// ---------------------------------------------------------------------------
// K3: per-(n,g) closed-form value: gval = 2*c_g*T_g - 2*||S_g||^2.
// ---------------------------------------------------------------------------
__global__ __launch_bounds__(256) void pergroup_kernel(const float* __restrict__ Spart,
                                                       const float* __restrict__ Tpart,
                                                       const int*   __restrict__ seg,
                                                       double* __restrict__ gval) {
    __shared__ double red[256];
    __shared__ int cl[4];
    int bid = blockIdx.x;
    int n = bid >> 4, g = bid & 15;
    int t = threadIdx.x;

    const int* segb = seg + n * L;
    int cnt = 0;
    for (int i = t; i < L; i += 256) cnt += (segb[i] == g);
    #pragma unroll
    for (int off = 32; off > 0; off >>= 1) cnt += __shfl_down(cnt, off);
    if ((t & 63) == 0) cl[t >> 6] = cnt;
    __syncthreads();
    int c_g = cl[0] + cl[1] + cl[2] + cl[3];

    double a = 0.0;
    for (int dg = t; dg < 512; dg += 256) {
        int c = dg >> 5, dd = dg & 31;
        float s = 0.0f;
        #pragma unroll
        for (int q = 0; q < 4; ++q)
            s += Spart[((size_t)(q * 128 + c * 8 + n) * 16 + g) * 32 + dd];
        a -= 2.0 * (double)s * (double)s;
    }
    if (t < 64) {
        int q = t >> 4, c = t & 15;
        a += 2.0 * (double)c_g * (double)Tpart[(q * 128 + c * 8 + n) * 16 + g];
    }
    red[t] = a;
    __syncthreads();
    #pragma unroll
    for (int s2 = 128; s2 > 0; s2 >>= 1) {
        if (t < s2) red[t] += red[t + s2];
        __syncthreads();
    }
    if (t == 0) gval[bid] = red[0];
}

// ---------------------------------------------------------------------------
// K4: final assembly: sum 128 gval + 1088 hpart -> loss.
// ---------------------------------------------------------------------------
__global__ __launch_bounds__(256) void final_kernel(const double* __restrict__ gval,
                                                    const double* __restrict__ hpart,
                                                    float* __restrict__ out) {
    __shared__ double red[256];
    int t = threadIdx.x;
    double a = 0.0;
    if (t < 128) a = ALPHA * gval[t];
    for (int i = t; i < SCREEN_BLOCKS; i += 256) a += BETA * hpart[i];
    red[t] = a;
    __syncthreads();
    #pragma unroll
    for (int s2 = 128; s2 > 0; s2 >>= 1) {
        if (t < s2) red[t] += red[t + s2];
        __syncthreads();
    }
    if (t == 0)
        out[0] = (float)(red[0] / ((double)NBATCH * (double)L * (double)L));
}

extern "C" void kernel_launch(void* const* d_in, const int* in_sizes, int n_in,
                              void* d_out, int out_size, void* d_ws, size_t ws_size,
                              hipStream_t stream) {
    const float* pred = (const float*)d_in[0];
    const int*   seg  = (const int*)d_in[1];
    float* out = (float*)d_out;

    unsigned char* h8 = (unsigned char*)d_ws;                  // 1 MB packed fp8
    float* Spart      = (float*)(h8 + 512 * PAN2);             // 1 MB
    float* Tpart      = Spart + 512 * 16 * 32;                 // 32 KB
    float* sqh        = Tpart + 512 * 16;                      // 128 KB (2 halves)
    double* hpart     = (double*)(sqh + 2 * NL);               // 8.7 KB
    double* gval      = hpart + SCREEN_BLOCKS;                 // 1 KB

    fused_kernel<<<512, 256, 0, stream>>>(pred, seg, Spart, Tpart, sqh, h8);
    screen_kernel<<<SCREEN_BLOCKS, 256, 0, stream>>>(h8, sqh, seg, pred, hpart);
    pergroup_kernel<<<128, 256, 0, stream>>>(Spart, Tpart, seg, gval);
    final_kernel<<<1, 256, 0, stream>>>(gval, hpart, out);
}

// Round 26
// 64.937 us; speedup vs baseline: 1.2676x; 1.2676x over previous
//
#include <hip/hip_runtime.h>
#include <hip/hip_fp8.h>
#include <math.h>

#define L      2048
#define DDIM   512
#define NBATCH 8
#define NL     (NBATCH * L)
#define NTILE  16
#define NPAIR  (NTILE * (NTILE + 1) / 2) // 136
#define SCREEN_BLOCKS (NBATCH * NPAIR)   // 1088

#define ALPHA  0.1
#define BETA   0.3
#define PAN2   2048      // bytes per packed 32-row x 64-dim fp8 panel

typedef __attribute__((ext_vector_type(16))) float f32x16;
typedef long long2v __attribute__((ext_vector_type(2)));

// ---------------------------------------------------------------------------
// K1 (streaming): contiguous float4 reads. Block = (n, c in 4 x 128 dims,
// qtr in 8 x 256 rows); 256 thr = 8 p-slots x 32 dim-lanes. Outputs:
//  - Spart[bid][16][128]: per-dim group sums (LDS-RMW float4, p-separated)
//  - rowsqPart[c][row]: per-row sq over this 128-dim chunk (shfl reduce)
//  - c==0 blocks: fp8 pack of dims 0..63 (R20-verified layout) + sq64
// ---------------------------------------------------------------------------
__global__ __launch_bounds__(256) void stream_kernel(const float* __restrict__ pred,
                                                     const int*   __restrict__ seg,
                                                     float* __restrict__ Spart,
                                                     float* __restrict__ rowsqPart,
                                                     float* __restrict__ sq64,
                                                     unsigned char* __restrict__ h8) {
    __shared__ float Sl[8][16][128];   // 64 KB

    int bid = blockIdx.x;
    int n   = bid & 7;
    int cc  = (bid >> 3) & 3;
    int qtr = bid >> 5;                // 0..7 (256-row group)
    int t = threadIdx.x;
    int d32 = t & 31;                  // dim-lane: float4 at cc*128 + d32*4
    int p   = t >> 5;                  // 0..7 row-slot

    for (int i = t; i < 8 * 16 * 128; i += 256) ((float*)Sl)[i] = 0.0f;
    __syncthreads();

    const float* pb   = pred + (size_t)n * L * DDIM + cc * 128 + d32 * 4;
    const int*   segb = seg + n * L;
    const bool packer = (cc == 0) && (d32 < 16);

    float* rspc = rowsqPart + (size_t)cc * NL + n * L;

    #pragma unroll 2
    for (int i = 0; i < 32; ++i) {
        int row = qtr * 256 + i * 8 + p;
        float4 x4 = *(const float4*)(pb + (size_t)row * DDIM);
        int g = segb[row];

        // per-dim group sums (float4 LDS-RMW; p-slot + row-uniform g -> no race)
        float4* slot = (float4*)&Sl[p][g][d32 * 4];
        float4 cur = *slot;
        cur.x += x4.x; cur.y += x4.y; cur.z += x4.z; cur.w += x4.w;
        *slot = cur;

        // per-row sq partial over this 128-dim chunk
        float rs = x4.x * x4.x + x4.y * x4.y + x4.z * x4.z + x4.w * x4.w;
        float rr = rs;
        #pragma unroll
        for (int off = 16; off > 0; off >>= 1) rr += __shfl_down(rr, off, 32);
        if (d32 == 0) rspc[row] = rr;

        // fp8 pack of dims 0..63 (c==0, d32<16) + sq64
        if (cc == 0) {
            float s64 = (d32 < 16) ? rs : 0.0f;
            #pragma unroll
            for (int off = 8; off > 0; off >>= 1) s64 += __shfl_down(s64, off, 16);
            if ((t & 15) == 0 && d32 < 16) sq64[n * L + row] = s64;
            unsigned b4 = 0;
            if (d32 < 16) {
                __hip_fp8_e4m3 f0(x4.x), f1(x4.y), f2(x4.z), f3(x4.w);
                b4 = (unsigned)f0.__x | ((unsigned)f1.__x << 8)
                   | ((unsigned)f2.__x << 16) | ((unsigned)f3.__x << 24);
            }
            unsigned other = __shfl_down(b4, 1, 32);
            if ((d32 & 1) == 0 && d32 < 16) {
                int u = d32 >> 1;                  // 8-dim unit 0..7
                int pair  = u >> 2;
                int kodd  = (u >> 1) & 1;
                int khalf = u & 1;
                size_t off = (size_t)(n * 64 + ((qtr * 256 + i * 8 + p) >> 5)) * PAN2
                           + pair * 1024 + ((row & 31) + 32 * khalf) * 16 + kodd * 8;
                *(uint2*)(h8 + off) = make_uint2(b4, other);
            }
        }
    }
    __syncthreads();

    // reduce p-slots -> Spart[bid][g][dd]
    float* sp = Spart + (size_t)bid * 2048;
    for (int i = t; i < 2048; i += 256) {
        int g = i >> 7, dd = i & 127;
        float s = 0.0f;
        #pragma unroll
        for (int q = 0; q < 8; ++q) s += Sl[q][g][dd];
        sp[i] = s;
    }
}

// ---------------------------------------------------------------------------
// K2: 64-dim fp8 screen GEMM (register-direct, verified frag mapping).
// LDS prologue stages seg + sq64 for the block's 256 rows. Certifies
// hinge==0 when d2e >= 4.5 + 0.27*nj*nk; survivors -> exact fp32 fallback.
// Per-block partial -> hpart[bid] (unconditional write, no atomics).
// ---------------------------------------------------------------------------
__global__ __launch_bounds__(256) void screen_kernel(
        const unsigned char* __restrict__ h8,
        const float* __restrict__ sq64,
        const int*   __restrict__ seg,
        const float* __restrict__ pred,
        double* __restrict__ hpart) {
    __shared__ float sqn[256];
    __shared__ float nn[256];
    __shared__ int   sgl[256];
    __shared__ double wred[4];

    int bid = blockIdx.x;
    int n = bid & 7;
    int p = bid >> 3;
    int tj = 0;
    while (true) {
        int rl2 = NTILE - tj;
        if (p < rl2) break;
        p -= rl2;
        ++tj;
    }
    int tk = tj + p;

    int t    = threadIdx.x;
    int wid  = t >> 6;
    int lane = t & 63;
    int wr   = wid >> 1, wc = wid & 1;
    int l31  = lane & 31;
    int hsel = lane >> 5;

    {
        int r = (t < 128) ? (tj * 128 + t) : (tk * 128 + (t - 128));
        float s = sq64[n * L + r];
        sqn[t] = s;
        nn[t]  = sqrtf(s);
        sgl[t] = seg[n * L + r];
    }
    __syncthreads();

    const unsigned char* pa0 = h8 + (size_t)(n * 64 + tj * 4 + wr * 2 + 0) * PAN2 + lane * 16;
    const unsigned char* pa1 = pa0 + PAN2;
    const unsigned char* pb0 = h8 + (size_t)(n * 64 + tk * 4 + wc * 2 + 0) * PAN2 + lane * 16;
    const unsigned char* pb1 = pb0 + PAN2;

    f32x16 acc[2][2];
    #pragma unroll
    for (int m = 0; m < 2; ++m)
        #pragma unroll
        for (int nf = 0; nf < 2; ++nf)
            #pragma unroll
            for (int x = 0; x < 16; ++x) acc[m][nf][x] = 0.0f;

    #pragma unroll
    for (int ks2 = 0; ks2 < 2; ++ks2) {
        long2v a0 = *(const long2v*)(pa0 + ks2 * 1024);
        long2v a1 = *(const long2v*)(pa1 + ks2 * 1024);
        long2v b0 = *(const long2v*)(pb0 + ks2 * 1024);
        long2v b1 = *(const long2v*)(pb1 + ks2 * 1024);
        acc[0][0] = __builtin_amdgcn_mfma_f32_32x32x16_fp8_fp8(a0.x, b0.x, acc[0][0], 0, 0, 0);
        acc[0][1] = __builtin_amdgcn_mfma_f32_32x32x16_fp8_fp8(a0.x, b1.x, acc[0][1], 0, 0, 0);
        acc[1][0] = __builtin_amdgcn_mfma_f32_32x32x16_fp8_fp8(a1.x, b0.x, acc[1][0], 0, 0, 0);
        acc[1][1] = __builtin_amdgcn_mfma_f32_32x32x16_fp8_fp8(a1.x, b1.x, acc[1][1], 0, 0, 0);
        acc[0][0] = __builtin_amdgcn_mfma_f32_32x32x16_fp8_fp8(a0.y, b0.y, acc[0][0], 0, 0, 0);
        acc[0][1] = __builtin_amdgcn_mfma_f32_32x32x16_fp8_fp8(a0.y, b1.y, acc[0][1], 0, 0, 0);
        acc[1][0] = __builtin_amdgcn_mfma_f32_32x32x16_fp8_fp8(a1.y, b0.y, acc[1][0], 0, 0, 0);
        acc[1][1] = __builtin_amdgcn_mfma_f32_32x32x16_fp8_fp8(a1.y, b1.y, acc[1][1], 0, 0, 0);
    }

    double hsum = 0.0;
    #pragma unroll
    for (int nf = 0; nf < 2; ++nf) {
        int kl = wc * 64 + nf * 32 + l31;
        int k  = tk * 128 + kl;
        float sqk = sqn[128 + kl];
        float nk  = nn[128 + kl];
        int   sgk = sgl[128 + kl];
        #pragma unroll
        for (int m = 0; m < 2; ++m)
            #pragma unroll
            for (int x = 0; x < 16; ++x) {
                int jl = wr * 64 + m * 32 + (x & 3) + 8 * (x >> 2) + 4 * hsel;
                int j  = tj * 128 + jl;
                if (j >= k) continue;
                if (sgl[jl] == sgk) continue;
                float d2e = sqn[jl] + sqk - 2.0f * acc[m][nf][x];
                float thr = 4.5f + 0.27f * nn[jl] * nk;
                if (d2e >= thr) continue;          // certified hinge == 0
                const float* pj  = pred + (size_t)(n * L + j) * DDIM;
                const float* pk2 = pred + (size_t)(n * L + k) * DDIM;
                float d2x = 0.0f;
                for (int dd = 0; dd < DDIM; ++dd) {
                    float df = pj[dd] - pk2[dd];
                    d2x = fmaf(df, df, d2x);
                }
                if (d2x < 4.0f) {
                    float dist = sqrtf(d2x);
                    float hg = 2.0f - dist;
                    hsum += (double)hg * (double)hg * 2.0;
                }
            }
    }

    #pragma unroll
    for (int off = 32; off > 0; off >>= 1)
        hsum += __shfl_down(hsum, off);
    if (lane == 0) wred[wid] = hsum;
    __syncthreads();
    if (t == 0) hpart[bid] = (wred[0] + wred[1]) + (wred[2] + wred[3]);
}

// ---------------------------------------------------------------------------
// K3: per-(n,g): gval = 2*c_g*T_g - 2*||S_g||^2, with T_g from rowsqPart
// and counts from seg (no atomics, deterministic).
// ---------------------------------------------------------------------------
__global__ __launch_bounds__(256) void pergroup_kernel(const float* __restrict__ Spart,
                                                       const float* __restrict__ rowsqPart,
                                                       const int*   __restrict__ seg,
                                                       double* __restrict__ gval) {
    __shared__ double red[256];
    __shared__ int cl[4];
    int bid = blockIdx.x;
    int n = bid >> 4, g = bid & 15;
    int t = threadIdx.x;

    const int* segb = seg + n * L;
    int cnt = 0;
    double tacc = 0.0;
    for (int i = t; i < L; i += 256) {
        if (segb[i] == g) {
            ++cnt;
            size_t r = (size_t)n * L + i;
            float rs = rowsqPart[r] + rowsqPart[NL + r]
                     + rowsqPart[2 * (size_t)NL + r] + rowsqPart[3 * (size_t)NL + r];
            tacc += (double)rs;
        }
    }
    int cw = cnt;
    #pragma unroll
    for (int off = 32; off > 0; off >>= 1) cw += __shfl_down(cw, off);
    if ((t & 63) == 0) cl[t >> 6] = cw;
    __syncthreads();
    int c_g = cl[0] + cl[1] + cl[2] + cl[3];

    double a = 2.0 * (double)c_g * tacc;
    for (int D = t; D < 512; D += 256) {
        int c = D >> 7, dd = D & 127;
        float s = 0.0f;
        #pragma unroll
        for (int q = 0; q < 8; ++q)
            s += Spart[(size_t)((q * 4 + c) * 8 + n) * 2048 + g * 128 + dd];
        a -= 2.0 * (double)s * (double)s;
    }
    red[t] = a;
    __syncthreads();
    #pragma unroll
    for (int s2 = 128; s2 > 0; s2 >>= 1) {
        if (t < s2) red[t] += red[t + s2];
        __syncthreads();
    }
    if (t == 0) gval[bid] = red[0];
}

// ---------------------------------------------------------------------------
// K4: final assembly.
// ---------------------------------------------------------------------------
__global__ __launch_bounds__(256) void final_kernel(const double* __restrict__ gval,
                                                    const double* __restrict__ hpart,
                                                    float* __restrict__ out) {
    __shared__ double red[256];
    int t = threadIdx.x;
    double a = 0.0;
    if (t < 128) a = ALPHA * gval[t];
    for (int i = t; i < SCREEN_BLOCKS; i += 256) a += BETA * hpart[i];
    red[t] = a;
    __syncthreads();
    #pragma unroll
    for (int s2 = 128; s2 > 0; s2 >>= 1) {
        if (t < s2) red[t] += red[t + s2];
        __syncthreads();
    }
    if (t == 0)
        out[0] = (float)(red[0] / ((double)NBATCH * (double)L * (double)L));
}

extern "C" void kernel_launch(void* const* d_in, const int* in_sizes, int n_in,
                              void* d_out, int out_size, void* d_ws, size_t ws_size,
                              hipStream_t stream) {
    const float* pred = (const float*)d_in[0];
    const int*   seg  = (const int*)d_in[1];
    float* out = (float*)d_out;

    unsigned char* h8 = (unsigned char*)d_ws;                  // 1 MB packed fp8
    float* sq64       = (float*)(h8 + 512 * PAN2);             // 64 KB
    float* rowsqPart  = sq64 + NL;                             // 256 KB (4 x NL)
    float* Spart      = rowsqPart + 4 * NL;                    // 2 MB (256 x 2048)
    double* hpart     = (double*)(Spart + 256 * 2048);         // 8.7 KB
    double* gval      = hpart + SCREEN_BLOCKS;                 // 1 KB

    stream_kernel<<<256, 256, 0, stream>>>(pred, seg, Spart, rowsqPart, sq64, h8);
    screen_kernel<<<SCREEN_BLOCKS, 256, 0, stream>>>(h8, sq64, seg, pred, hpart);
    pergroup_kernel<<<128, 256, 0, stream>>>(Spart, rowsqPart, seg, gval);
    final_kernel<<<1, 256, 0, stream>>>(gval, hpart, out);
}